// Round 2
// baseline (543.655 us; speedup 1.0000x reference)
//
#include <hip/hip_runtime.h>

#define NTAG 128
#define SEQ 512
#define NBATCH 512
#define END_ID 1
#define GB 16          // batches per wave (MFMA N dimension)
#define EMARGIN 4      // renorm headroom bits (worst-case packed max ~2^13.4 < f16 max)

typedef _Float16 v8h __attribute__((ext_vector_type(8)));
typedef float f32x4 __attribute__((ext_vector_type(4)));
typedef __fp16 fp16x2 __attribute__((ext_vector_type(2)));

#define LOG2E 1.4426950408889634f
#define LN2   0.6931471805599453f

__device__ __forceinline__ uint pack2(float a, float b) {
  fp16x2 h = __builtin_amdgcn_cvt_pkrtz(a, b);
  return __builtin_bit_cast(uint, h);
}
__device__ __forceinline__ float fast_exp2(float x) {
#if __has_builtin(__builtin_amdgcn_exp2f)
  return __builtin_amdgcn_exp2f(x);
#else
  return exp2f(x);
#endif
}
__device__ __forceinline__ float fast_log2(float x) {
#if __has_builtin(__builtin_amdgcn_logf)
  return __builtin_amdgcn_logf(x);
#else
  return log2f(x);
#endif
}

// ROUND-10 KEY CHANGE: trans is batch-shared, so 16 batches ride one wave as
// the N dim of v_mfma_f32_16x16x32_f16: P' = (E.P) * exp(x). E' lives in 128
// AGPR-friendly regs that MFMA reads DIRECTLY (no v_accvgpr_read tax that
// capped rounds 0-9). With a consistent k-enumeration on the A- and B-pack
// sides (contraction is invariant under a shared k-permutation), the C/D
// fragment of step t IS the B fragment of step t+1 in the SAME lane/regs:
//   B_frag(ks) = [Dtile(2ks) rows h*4+0..3, Dtile(2ks+1) rows h*4+0..3]
// -> zero shuffles, zero LDS, zero barriers in the 509-step serial loop.
// Renorm: deferred exponent e (from prev step's max, off the critical chain),
// folded into exp2(x*log2e - (e+4)). M accumulates shifts; alpha = M + log2(p).
__global__ __launch_bounds__(64, 1) void crf_kernel(
    const float* __restrict__ x,      // [B,S,T]
    const int*   __restrict__ tags,   // [B,S]
    const float* __restrict__ mask,   // [B,S]
    const float* __restrict__ trans,  // [T,T]
    float* __restrict__ ws)           // [B]
{
  const int bg = blockIdx.x * GB;     // batch group base
  const int l  = threadIdx.x;         // 0..63
  const int m  = l & 15;              // batch-in-group (B/D col; A row-in-tile)
  const int h  = l >> 4;              // k-group / D row-group

  const int bb = bg + m;              // this lane's batch
  const float* xb   = x    + (size_t)bb * SEQ * NTAG;
  const int*   trow = tags + (size_t)bb * SEQ;

  // ---- len for batch bb: sum over mask row (h-lanes split the row) ----
  float msum = 0.f;
  {
    const float4* m4 = (const float4*)(mask + (size_t)bb * SEQ);
    #pragma unroll
    for (int k = 0; k < 32; ++k) {
      float4 v = m4[h * 32 + k];
      msum += (v.x + v.y) + (v.z + v.w);
    }
    msum += __shfl_xor(msum, 16);
    msum += __shfl_xor(msum, 32);
  }
  const int len = (int)msum;          // in [1, 509]
  int ml = len;
  #pragma unroll
  for (int off = 1; off < 64; off <<= 1) ml = max(ml, __shfl_xor(ml, off));
  const int maxlenE = (ml + 1) & ~1;  // even trip count for ping-pong unroll

  // ---- A fragments: E'[j,k] = exp(trans[j,k]), f16, k-enum kappa(h,r,e) =
  //      (r>>1)*16 + h*4 + (r&1)*2 + e  (same enum used on the B side) ----
  v8h Afr[8][4];                      // [mtile][kstep], 4 VGPRs each (AGPR-ok)
  #pragma unroll
  for (int mt = 0; mt < 8; ++mt) {
    const float* rowp = trans + (size_t)(mt * 16 + m) * NTAG;
    #pragma unroll
    for (int ks = 0; ks < 4; ++ks) {
      float4 c0 = *(const float4*)(rowp + ks * 32 + h * 4);
      float4 c1 = *(const float4*)(rowp + ks * 32 + 16 + h * 4);
      v8h a;
      a[0] = (_Float16)fast_exp2(c0.x * LOG2E);
      a[1] = (_Float16)fast_exp2(c0.y * LOG2E);
      a[2] = (_Float16)fast_exp2(c0.z * LOG2E);
      a[3] = (_Float16)fast_exp2(c0.w * LOG2E);
      a[4] = (_Float16)fast_exp2(c1.x * LOG2E);
      a[5] = (_Float16)fast_exp2(c1.y * LOG2E);
      a[6] = (_Float16)fast_exp2(c1.z * LOG2E);
      a[7] = (_Float16)fast_exp2(c1.w * LOG2E);
      Afr[mt][ks] = a;
    }
  }

  // ---- state: Pk (f16 B-fragments), shift accumulator M, exponent e ----
  v8h PkA[4], PkB[4];
  #pragma unroll
  for (int ks = 0; ks < 4; ++ks) {
    v8h z;
    #pragma unroll
    for (int i = 0; i < 8; ++i) z[i] = (_Float16)0.0f;
    PkA[ks] = z; PkB[ks] = z;
  }
  if (h == 0) PkA[0][0] = (_Float16)1.0f;   // p0 = delta(START_ID=0) -> j=0
  float M = 0.f;
  int eprev = 0;

  // ---- x prefetch: row t, lane needs cols {mt*16 + h*4 .. +3} ----
  const float4* xrow4 = (const float4*)xb;   // row t: xrow4[t*32 + mt*4 + h]
  float4 xA[8], xB[8];
  #pragma unroll
  for (int mt = 0; mt < 8; ++mt) xA[mt] = xrow4[mt * 4 + h];

  const f32x4 zero4 = {0.f, 0.f, 0.f, 0.f};

#define BODY(PS, PD, XC, XN, T_)                                              \
  {                                                                           \
    const int t_ = (T_);                                                      \
    const bool act = (t_ < len);                                              \
    _Pragma("unroll")                                                         \
    for (int mt = 0; mt < 8; ++mt)                                            \
      XN[mt] = xrow4[(size_t)(t_ + 1) * 32 + mt * 4 + h];                     \
    const float csh = (float)(eprev + EMARGIN);                               \
    float smax = 0.f;                                                         \
    uint pu[8][2];                                                            \
    _Pragma("unroll")                                                         \
    for (int mt = 0; mt < 8; ++mt) {                                          \
      f32x4 d = __builtin_amdgcn_mfma_f32_16x16x32_f16(Afr[mt][0], PS[0], zero4, 0, 0, 0); \
      d = __builtin_amdgcn_mfma_f32_16x16x32_f16(Afr[mt][1], PS[1], d, 0, 0, 0); \
      d = __builtin_amdgcn_mfma_f32_16x16x32_f16(Afr[mt][2], PS[2], d, 0, 0, 0); \
      d = __builtin_amdgcn_mfma_f32_16x16x32_f16(Afr[mt][3], PS[3], d, 0, 0, 0); \
      const float4 xv = XC[mt];                                               \
      const float v0 = d[0] * fast_exp2(fmaf(xv.x, LOG2E, -csh));             \
      const float v1 = d[1] * fast_exp2(fmaf(xv.y, LOG2E, -csh));             \
      const float v2 = d[2] * fast_exp2(fmaf(xv.z, LOG2E, -csh));             \
      const float v3 = d[3] * fast_exp2(fmaf(xv.w, LOG2E, -csh));             \
      smax = fmaxf(smax, fmaxf(fmaxf(v0, v1), fmaxf(v2, v3)));                \
      pu[mt][0] = pack2(v0, v1);                                              \
      pu[mt][1] = pack2(v2, v3);                                              \
    }                                                                         \
    _Pragma("unroll")                                                         \
    for (int ks = 0; ks < 4; ++ks) {                                          \
      uint4 q; q.x = pu[2 * ks][0]; q.y = pu[2 * ks][1];                      \
      q.z = pu[2 * ks + 1][0]; q.w = pu[2 * ks + 1][1];                       \
      const v8h nv = __builtin_bit_cast(v8h, q);                              \
      PD[ks] = act ? nv : PS[ks];                                             \
    }                                                                         \
    smax = fmaxf(smax, __shfl_xor(smax, 16));                                 \
    smax = fmaxf(smax, __shfl_xor(smax, 32));                                 \
    int en = ((__float_as_int(smax) >> 23) & 255) - 127;                      \
    en = en < -30 ? -30 : (en > 30 ? 30 : en);                                \
    M     = act ? (M + csh) : M;                                              \
    eprev = act ? en : eprev;                                                 \
  }

  for (int t = 0; t < maxlenE; t += 2) {
    BODY(PkA, PkB, xA, xB, t)
    BODY(PkB, PkA, xB, xA, t + 1)
  }
#undef BODY
  // final state in PkA (even number of bodies executed)

  // ---- fwd = logsumexp_j(alpha[j] + trans[END][j]); alpha = (M+log2 p)*ln2 ----
  const float* tE = trans + (size_t)END_ID * NTAG;
  float vv[4][8];
  float m2 = -3.4e38f;
  #pragma unroll
  for (int ks = 0; ks < 4; ++ks) {
    float4 te0 = *(const float4*)(tE + ks * 32 + h * 4);
    float4 te1 = *(const float4*)(tE + ks * 32 + 16 + h * 4);
    #pragma unroll
    for (int i = 0; i < 8; ++i) {
      const float p  = (float)PkA[ks][i];
      const float te = (i < 4)
          ? ((i & 3) == 0 ? te0.x : (i & 3) == 1 ? te0.y : (i & 3) == 2 ? te0.z : te0.w)
          : ((i & 3) == 0 ? te1.x : (i & 3) == 1 ? te1.y : (i & 3) == 2 ? te1.z : te1.w);
      const float v = (M + fast_log2(p)) * LN2 + te;   // p==0 -> -inf, ok
      vv[ks][i] = v;
      m2 = fmaxf(m2, v);
    }
  }
  m2 = fmaxf(m2, __shfl_xor(m2, 16));
  m2 = fmaxf(m2, __shfl_xor(m2, 32));
  float s = 0.f;
  #pragma unroll
  for (int ks = 0; ks < 4; ++ks)
    #pragma unroll
    for (int i = 0; i < 8; ++i)
      s += fast_exp2((vv[ks][i] - m2) * LOG2E);
  s += __shfl_xor(s, 16);
  s += __shfl_xor(s, 32);
  const float fwd = m2 + fast_log2(s) * LN2;

  // ---- gold score (4 h-lanes per batch, strided) ----
  float g = 0.f;
  for (int i = h; i < len; i += 4) {
    const int tn = trow[i + 1];
    const int tp = trow[i];
    g += xb[(size_t)i * NTAG + tn] + trans[(size_t)tn * NTAG + tp];
  }
  g += __shfl_xor(g, 16);
  g += __shfl_xor(g, 32);

  if (h == 0) {
    const float gold = g + trans[(size_t)END_ID * NTAG + trow[len]];
    ws[bb] = fwd - gold;
  }
}

__global__ void reduce_kernel(const float* __restrict__ ws, float* __restrict__ out) {
  __shared__ float sm[8];
  const int tid = threadIdx.x;   // 512
  float v = ws[tid];
  #pragma unroll
  for (int off = 1; off < 64; off <<= 1) v += __shfl_xor(v, off);
  if ((tid & 63) == 0) sm[tid >> 6] = v;
  __syncthreads();
  if (tid == 0) {
    float s = 0.f;
    #pragma unroll
    for (int w = 0; w < 8; ++w) s += sm[w];
    out[0] = s * (1.0f / 512.0f);
  }
}

extern "C" void kernel_launch(void* const* d_in, const int* in_sizes, int n_in,
                              void* d_out, int out_size, void* d_ws, size_t ws_size,
                              hipStream_t stream) {
  const float* x     = (const float*)d_in[0];
  const int*   tags  = (const int*)d_in[1];
  const float* mask  = (const float*)d_in[2];
  const float* trans = (const float*)d_in[3];
  float*       ws    = (float*)d_ws;

  crf_kernel<<<NBATCH / GB, 64, 0, stream>>>(x, tags, mask, trans, ws);
  reduce_kernel<<<1, 512, 0, stream>>>(ws, (float*)d_out);
}

// Round 3
// 483.943 us; speedup vs baseline: 1.1234x; 1.1234x over previous
//
#include <hip/hip_runtime.h>

#define NTAG 128
#define SEQ 512
#define NBATCH 512
#define END_ID 1
#define GB 16          // batches per group (MFMA N dimension)
#define NW 8           // waves per block: one 16-row j-tile each
#define EMARGIN 4      // renorm headroom bits

typedef _Float16 v8h __attribute__((ext_vector_type(8)));
typedef _Float16 h2v __attribute__((ext_vector_type(2)));
typedef float f32x4 __attribute__((ext_vector_type(4)));
typedef __fp16 fp16x2 __attribute__((ext_vector_type(2)));

#define LOG2E 1.4426950408889634f
#define LN2   0.6931471805599453f

__device__ __forceinline__ uint pack2(float a, float b) {
  fp16x2 h = __builtin_amdgcn_cvt_pkrtz(a, b);
  return __builtin_bit_cast(uint, h);
}
__device__ __forceinline__ float fast_exp2(float x) {
#if __has_builtin(__builtin_amdgcn_exp2f)
  return __builtin_amdgcn_exp2f(x);
#else
  return exp2f(x);
#endif
}
__device__ __forceinline__ float fast_log2(float x) {
#if __has_builtin(__builtin_amdgcn_logf)
  return __builtin_amdgcn_logf(x);
#else
  return log2f(x);
#endif
}
__device__ __forceinline__ v8h vmax8(v8h a, v8h b) {
#if __has_builtin(__builtin_elementwise_max)
  return __builtin_elementwise_max(a, b);
#else
  v8h r;
  #pragma unroll
  for (int i = 0; i < 8; ++i) r[i] = a[i] > b[i] ? a[i] : b[i];
  return r;
#endif
}
__device__ __forceinline__ uint hmax2u(uint a, uint b) {
#if __has_builtin(__builtin_elementwise_max)
  h2v r = __builtin_elementwise_max(__builtin_bit_cast(h2v, a),
                                    __builtin_bit_cast(h2v, b));
  return __builtin_bit_cast(uint, r);
#else
  h2v x = __builtin_bit_cast(h2v, a), y = __builtin_bit_cast(h2v, b);
  h2v r; r[0] = x[0] > y[0] ? x[0] : y[0]; r[1] = x[1] > y[1] ? x[1] : y[1];
  return __builtin_bit_cast(uint, r);
#endif
}

// ROUND-11 KEY CHANGE: keep round-10's MFMA recurrence (P' = (E.P)*exp(x),
// D->B fragment identity, per-batch deferred-exponent renorm) but split the
// 8 j-tiles across 8 WAVES (round 10 put all 32 MFMAs in ONE wave: issue
// alone = 620 cyc/step on one SIMD, chain fully exposed, 1890 cyc/step
// measured). Each wave: 4 C-chained MFMAs; new P exchanged via
// double-buffered LDS, ONE barrier/step. Renorm exponent computed on the
// READ side (pk-max tree over the read B-frags, per batch column), so no
// cross-wave max exchange. A-table: 16 VGPRs/wave. x prefetch clamped to
// per-batch len (round 10 streamed to group-max len: 2x over-fetch).
__global__ __launch_bounds__(NW * 64, 1) void crf_kernel(
    const float* __restrict__ x,      // [B,S,T]
    const int*   __restrict__ tags,   // [B,S]
    const float* __restrict__ mask,   // [B,S]
    const float* __restrict__ trans,  // [T,T]
    float* __restrict__ ws)           // [B]
{
  const int bg = blockIdx.x * GB;
  const int tidx = threadIdx.x;
  const int w = tidx >> 6;            // wave = j-tile 0..7
  const int l = tidx & 63;
  const int m = l & 15;               // batch-in-group (B/D column)
  const int h = l >> 4;               // k-group / D row-group
  const int bb = bg + m;

  __shared__ uint4 pbuf[2][4][64];    // [buf][ks][lane] packed B-fragments

  const float* xb   = x    + (size_t)bb * SEQ * NTAG;
  const int*   trow = tags + (size_t)bb * SEQ;

  // ---- len for batch bb ----
  float msum = 0.f;
  {
    const float4* m4 = (const float4*)(mask + (size_t)bb * SEQ);
    #pragma unroll
    for (int k = 0; k < 32; ++k) {
      float4 v = m4[h * 32 + k];
      msum += (v.x + v.y) + (v.z + v.w);
    }
    msum += __shfl_xor(msum, 16);
    msum += __shfl_xor(msum, 32);
  }
  const int len = (int)msum;          // in [1, 509]
  int ml = len;
  #pragma unroll
  for (int off = 1; off < 64; off <<= 1) ml = max(ml, __shfl_xor(ml, off));
  const int maxlen4 = (ml + 3) & ~3;  // multiple of 4 (ring depth)

  // ---- A frags for tile w: E'[w*16+m, k] = exp(trans), k-enum kappa =
  //      ks*32 + (e>=4)*16 + h*4 + (e&3)  (same enum as B side) ----
  v8h Af[4];
  {
    const float* rowp = trans + (size_t)(w * 16 + m) * NTAG;
    #pragma unroll
    for (int ks = 0; ks < 4; ++ks) {
      float4 c0 = *(const float4*)(rowp + ks * 32 + h * 4);
      float4 c1 = *(const float4*)(rowp + ks * 32 + 16 + h * 4);
      v8h a;
      a[0] = (_Float16)fast_exp2(c0.x * LOG2E);
      a[1] = (_Float16)fast_exp2(c0.y * LOG2E);
      a[2] = (_Float16)fast_exp2(c0.z * LOG2E);
      a[3] = (_Float16)fast_exp2(c0.w * LOG2E);
      a[4] = (_Float16)fast_exp2(c1.x * LOG2E);
      a[5] = (_Float16)fast_exp2(c1.y * LOG2E);
      a[6] = (_Float16)fast_exp2(c1.z * LOG2E);
      a[7] = (_Float16)fast_exp2(c1.w * LOG2E);
      Af[ks] = a;
    }
  }

  // ---- init P frags (p0 = delta at k=0 -> ks=0, h=0, elem 0) ----
  if (w == 0) {
    #pragma unroll
    for (int ks = 0; ks < 4; ++ks) {
      uint4 z; z.x = 0u; z.y = 0u; z.z = 0u; z.w = 0u;
      if (ks == 0 && h == 0) z.x = 0x00003C00u;   // f16 1.0 in low half
      pbuf[0][ks][l] = z;
    }
  }
  float M = 0.f;

  // ---- x ring (depth 4); lane reads x[bb][t][w*16 + h*4 .. +3] ----
  const float* xj = xb + w * 16 + h * 4;
  float4 xf0 = *(const float4*)(xj + 0 * NTAG);
  float4 xf1 = *(const float4*)(xj + 1 * NTAG);
  float4 xf2 = *(const float4*)(xj + 2 * NTAG);
  float4 xf3 = *(const float4*)(xj + 3 * NTAG);

  __syncthreads();

  const f32x4 zero4 = {0.f, 0.f, 0.f, 0.f};

#define CRF_STEP(XF, S_)                                                      \
  {                                                                           \
    const int t_  = t + (S_);                                                 \
    const int pp_ = t_ & 1;                                                   \
    const bool act = (t_ < len);                                              \
    const uint4 q0 = pbuf[pp_][0][l];                                         \
    const uint4 q1 = pbuf[pp_][1][l];                                         \
    const uint4 q2 = pbuf[pp_][2][l];                                         \
    const uint4 q3 = pbuf[pp_][3][l];                                         \
    const uint2 oldv = ((const uint2*)&pbuf[pp_][w >> 1][l])[w & 1];          \
    const float4 xv = XF;                                                     \
    XF = *(const float4*)(xj + (size_t)min(t_ + 4, len) * NTAG);              \
    f32x4 d = __builtin_amdgcn_mfma_f32_16x16x32_f16(                         \
        Af[0], __builtin_bit_cast(v8h, q0), zero4, 0, 0, 0);                  \
    d = __builtin_amdgcn_mfma_f32_16x16x32_f16(                               \
        Af[1], __builtin_bit_cast(v8h, q1), d, 0, 0, 0);                      \
    d = __builtin_amdgcn_mfma_f32_16x16x32_f16(                               \
        Af[2], __builtin_bit_cast(v8h, q2), d, 0, 0, 0);                      \
    d = __builtin_amdgcn_mfma_f32_16x16x32_f16(                               \
        Af[3], __builtin_bit_cast(v8h, q3), d, 0, 0, 0);                      \
    /* per-batch-column renorm exponent from the read frags (lag-0) */        \
    v8h mt0 = vmax8(__builtin_bit_cast(v8h, q0), __builtin_bit_cast(v8h, q1));\
    v8h mt1 = vmax8(__builtin_bit_cast(v8h, q2), __builtin_bit_cast(v8h, q3));\
    v8h mt2 = vmax8(mt0, mt1);                                                \
    const uint4 tu = __builtin_bit_cast(uint4, mt2);                          \
    uint mu = hmax2u(hmax2u(tu.x, tu.y), hmax2u(tu.z, tu.w));                 \
    mu = hmax2u(mu, (uint)__shfl_xor((int)mu, 16));                           \
    mu = hmax2u(mu, (uint)__shfl_xor((int)mu, 32));                           \
    const h2v mh = __builtin_bit_cast(h2v, mu);                               \
    const float fm = fmaxf((float)mh[0], (float)mh[1]);                       \
    int e_ = ((__float_as_int(fm) >> 23) & 255) - 127;                        \
    e_ = e_ < -30 ? -30 : (e_ > 30 ? 30 : e_);                                \
    const float csh = (float)(e_ + EMARGIN);                                  \
    const float v0 = d[0] * fast_exp2(fmaf(xv.x, LOG2E, -csh));               \
    const float v1 = d[1] * fast_exp2(fmaf(xv.y, LOG2E, -csh));               \
    const float v2 = d[2] * fast_exp2(fmaf(xv.z, LOG2E, -csh));               \
    const float v3 = d[3] * fast_exp2(fmaf(xv.w, LOG2E, -csh));               \
    uint2 wr;                                                                 \
    wr.x = act ? pack2(v0, v1) : oldv.x;                                      \
    wr.y = act ? pack2(v2, v3) : oldv.y;                                      \
    ((uint2*)&pbuf[pp_ ^ 1][w >> 1][l])[w & 1] = wr;                          \
    M = act ? (M + csh) : M;                                                  \
    __syncthreads();                                                          \
  }

  for (int t = 0; t < maxlen4; t += 4) {
    CRF_STEP(xf0, 0)
    CRF_STEP(xf1, 1)
    CRF_STEP(xf2, 2)
    CRF_STEP(xf3, 3)
  }
#undef CRF_STEP
  // final P is in pbuf[0] (maxlen4 is a multiple of 4 -> even step count)

  if (w == 0) {
    v8h Pk[4];
    #pragma unroll
    for (int ks = 0; ks < 4; ++ks)
      Pk[ks] = __builtin_bit_cast(v8h, pbuf[0][ks][l]);

    // ---- fwd = logsumexp_j(alpha[j] + trans[END][j]); alpha=(M+log2 p)ln2 ----
    const float* tE = trans + (size_t)END_ID * NTAG;
    float vv[4][8];
    float m2 = -3.4e38f;
    #pragma unroll
    for (int ks = 0; ks < 4; ++ks) {
      float4 te0 = *(const float4*)(tE + ks * 32 + h * 4);
      float4 te1 = *(const float4*)(tE + ks * 32 + 16 + h * 4);
      #pragma unroll
      for (int i = 0; i < 8; ++i) {
        const float p  = (float)Pk[ks][i];
        const float te = (i < 4)
            ? ((i & 3) == 0 ? te0.x : (i & 3) == 1 ? te0.y : (i & 3) == 2 ? te0.z : te0.w)
            : ((i & 3) == 0 ? te1.x : (i & 3) == 1 ? te1.y : (i & 3) == 2 ? te1.z : te1.w);
        const float v = (M + fast_log2(p)) * LN2 + te;   // p==0 -> -inf, ok
        vv[ks][i] = v;
        m2 = fmaxf(m2, v);
      }
    }
    m2 = fmaxf(m2, __shfl_xor(m2, 16));
    m2 = fmaxf(m2, __shfl_xor(m2, 32));
    float s = 0.f;
    #pragma unroll
    for (int ks = 0; ks < 4; ++ks)
      #pragma unroll
      for (int i = 0; i < 8; ++i)
        s += fast_exp2((vv[ks][i] - m2) * LOG2E);
    s += __shfl_xor(s, 16);
    s += __shfl_xor(s, 32);
    const float fwd = m2 + fast_log2(s) * LN2;

    // ---- gold score (4 h-lanes per batch, strided) ----
    float g = 0.f;
    for (int i = h; i < len; i += 4) {
      const int tn = trow[i + 1];
      const int tp = trow[i];
      g += xb[(size_t)i * NTAG + tn] + trans[(size_t)tn * NTAG + tp];
    }
    g += __shfl_xor(g, 16);
    g += __shfl_xor(g, 32);

    if (h == 0) {
      const float gold = g + trans[(size_t)END_ID * NTAG + trow[len]];
      ws[bb] = fwd - gold;
    }
  }
}

__global__ void reduce_kernel(const float* __restrict__ ws, float* __restrict__ out) {
  __shared__ float sm[8];
  const int tid = threadIdx.x;   // 512
  float v = ws[tid];
  #pragma unroll
  for (int off = 1; off < 64; off <<= 1) v += __shfl_xor(v, off);
  if ((tid & 63) == 0) sm[tid >> 6] = v;
  __syncthreads();
  if (tid == 0) {
    float s = 0.f;
    #pragma unroll
    for (int w = 0; w < 8; ++w) s += sm[w];
    out[0] = s * (1.0f / 512.0f);
  }
}

extern "C" void kernel_launch(void* const* d_in, const int* in_sizes, int n_in,
                              void* d_out, int out_size, void* d_ws, size_t ws_size,
                              hipStream_t stream) {
  const float* x     = (const float*)d_in[0];
  const int*   tags  = (const int*)d_in[1];
  const float* mask  = (const float*)d_in[2];
  const float* trans = (const float*)d_in[3];
  float*       ws    = (float*)d_ws;

  crf_kernel<<<NBATCH / GB, NW * 64, 0, stream>>>(x, tags, mask, trans, ws);
  reduce_kernel<<<1, 512, 0, stream>>>(ws, (float*)d_out);
}